// Round 10
// baseline (716.457 us; speedup 1.0000x reference)
//
#include <hip/hip_runtime.h>

#define EPS 1e-5f
#define WROWS 480   // LDS window rows; 480*80B = 37.5KB -> 4 blocks/CU

typedef __attribute__((ext_vector_type(8))) short short8;            // 8 bf16 MFMA frag
typedef __attribute__((ext_vector_type(4))) float floatx4;           // MFMA C/D frag
typedef __attribute__((ext_vector_type(8))) unsigned short ushort8;
typedef __attribute__((ext_vector_type(4))) unsigned short ushortv4;

// packed-weight element offsets (compile-time)
#define O_S1  0
#define O_S2  4096
#define O_DN  (O_S2 + 27648)
#define O_R1A (O_DN + 8192)
#define O_R1B (O_R1A + 27648)
#define O_R2A (O_R1B + 27648)
#define O_R2B (O_R2A + 27648)
#define WP_TOTAL (O_R2B + 27648)

// bf16 <-> f32 (RTNE)
__device__ __forceinline__ unsigned short f2bf(float f) {
    union { float f; unsigned u; } x; x.f = f;
    unsigned r = x.u + 0x7fffu + ((x.u >> 16) & 1u);
    return (unsigned short)(r >> 16);
}
__device__ __forceinline__ float bf2f(unsigned short b) {
    union { unsigned u; float f; } x; x.u = ((unsigned)b) << 16;
    return x.f;
}

// XCD-aware block remap [R8: halved FETCH] — also makes per-block row spans
// contiguous, which the LDS window staging below depends on for small spans.
__device__ __forceinline__ int xcd_swizzle(int nb) {
    int b = (int)blockIdx.x;
    int q = nb >> 3, r = nb & 7;
    int x = b & 7, i = b >> 3;
    return x * q + (x < r ? x : r) + i;
}

// guarded 16B A-fragment gather from GLOBAL (fallback path)
__device__ __forceinline__ short8 gath(const unsigned short* __restrict__ x,
                                       int ii, int q) {
    short8 z = {};
    return (ii >= 0) ? *(const short8*)(x + (size_t)ii * 32 + q * 8) : z;
}

// ---------------------------------------------------------------------------
// One fused prep launch: cvt vf->bf16, pack stem1 W, pack six CI=32 W sets.
__device__ __forceinline__ void pack_w_one(
    const float* __restrict__ W, unsigned short* __restrict__ out, int t)
{
    int lane = t & 63;
    int h = (t >> 6) & 1;
    int k = t >> 7;
    int m = lane & 15, q = lane >> 4;
    ushort8 v;
#pragma unroll
    for (int j = 0; j < 8; ++j)
        v[j] = f2bf(W[((size_t)k * 32 + q * 8 + j) * 32 + h * 16 + m]);
    *(ushort8*)(out + (size_t)t * 8) = v;
}

__global__ __launch_bounds__(256) void prep_kernel(
    const float* __restrict__ vf,
    const float* __restrict__ Ws1, const float* __restrict__ Ws2,
    const float* __restrict__ Wd,  const float* __restrict__ Wr1a,
    const float* __restrict__ Wr1b, const float* __restrict__ Wr2a,
    const float* __restrict__ Wr2b,
    unsigned short* __restrict__ xb, unsigned short* __restrict__ wp, int N0)
{
    int t = blockIdx.x * 256 + threadIdx.x;
    if (t < N0) {                                   // cvt vf -> bf16
        float4 v = *(const float4*)(vf + (size_t)t * 4);
        ushortv4 r = {f2bf(v.x), f2bf(v.y), f2bf(v.z), f2bf(v.w)};
        *(ushortv4*)(xb + (size_t)t * 4) = r;
        return;
    }
    t -= N0;
    if (t < 512) {                                  // stem1 pack (taps folded into K)
        int lane = t & 63;
        int h = (t >> 6) & 1;
        int c = t >> 7;
        int m = lane & 15, q = lane >> 4;
        ushort8 v;
#pragma unroll
        for (int j = 0; j < 8; ++j) {
            int kdim = c * 32 + q * 8 + j;
            int tap = kdim >> 2, ci = kdim & 3;
            v[j] = (tap < 27) ? f2bf(Ws1[((size_t)tap * 4 + ci) * 32 + h * 16 + m]) : 0;
        }
        *(ushort8*)(wp + O_S1 + (size_t)t * 8) = v;
        return;
    }
    t -= 512;
    if (t < 27 * 128) { pack_w_one(Ws2,  wp + O_S2,  t); return; }
    t -= 27 * 128;
    if (t < 8 * 128)  { pack_w_one(Wd,   wp + O_DN,  t); return; }
    t -= 8 * 128;
    if (t < 27 * 128) { pack_w_one(Wr1a, wp + O_R1A, t); return; }
    t -= 27 * 128;
    if (t < 27 * 128) { pack_w_one(Wr1b, wp + O_R1B, t); return; }
    t -= 27 * 128;
    if (t < 27 * 128) { pack_w_one(Wr2a, wp + O_R2A, t); return; }
    t -= 27 * 128;
    if (t < 27 * 128) { pack_w_one(Wr2b, wp + O_R2B, t); return; }
}

// ---------------------------------------------------------------------------
// Epilogue (2-tile / stem1): C-layout stores + BN partials -> LDS -> part[lb].
__device__ __forceinline__ void conv_epilogue2(
    floatx4 acc00, floatx4 acc01, floatx4 acc10, floatx4 acc11,
    unsigned short* __restrict__ y, float* __restrict__ part,
    int rowbase, int lb, int N, float* sm)
{
    const int lane = threadIdx.x & 63;
    const int m = lane & 15, q = lane >> 4;

    if (threadIdx.x < 64) sm[threadIdx.x] = 0.f;
    __syncthreads();

#pragma unroll
    for (int r = 0; r < 4; ++r) {
        int ra = rowbase + q * 4 + r;
        int rb = ra + 16;
        if (ra < N) {
            y[(size_t)ra * 32 + m]      = f2bf(acc00[r]);
            y[(size_t)ra * 32 + 16 + m] = f2bf(acc01[r]);
        }
        if (rb < N) {
            y[(size_t)rb * 32 + m]      = f2bf(acc10[r]);
            y[(size_t)rb * 32 + 16 + m] = f2bf(acc11[r]);
        }
    }

    float s0 = 0.f, q0 = 0.f, s1 = 0.f, q1 = 0.f;
#pragma unroll
    for (int r = 0; r < 4; ++r) {
        s0 += acc00[r] + acc10[r];
        q0 += acc00[r] * acc00[r] + acc10[r] * acc10[r];
        s1 += acc01[r] + acc11[r];
        q1 += acc01[r] * acc01[r] + acc11[r] * acc11[r];
    }
    s0 += __shfl_down(s0, 32); s0 += __shfl_down(s0, 16);
    q0 += __shfl_down(q0, 32); q0 += __shfl_down(q0, 16);
    s1 += __shfl_down(s1, 32); s1 += __shfl_down(s1, 16);
    q1 += __shfl_down(q1, 32); q1 += __shfl_down(q1, 16);
    if (lane < 16) {
        atomicAdd(&sm[m],      s0);
        atomicAdd(&sm[32 + m], q0);
        atomicAdd(&sm[16 + m],      s1);
        atomicAdd(&sm[48 + m], q1);
    }
    __syncthreads();
    if (threadIdx.x < 64)
        part[(size_t)lb * 64 + threadIdx.x] = sm[threadIdx.x];
}

#define MFMA_BF16 __builtin_amdgcn_mfma_f32_16x16x32_bf16

// ---------------------------------------------------------------------------
// MFMA sparse conv with LDS WINDOW STAGING (round 10).
// [R9 evidence: TA/address-bound — 2x ILP at half occupancy gave same dur,
//  MfmaUtil 8%; divergent 64-addr gathers saturate the per-CU L1/TA path.]
// Taps group into x-triplets {g, g+S, g+2S} (x fastest in code order), whose
// neighbor rows for a contiguous 256-row block form a ~256-row window.
// Per group: block min/max of valid idx -> if span<=WROWS, stage window into
// LDS with coalesced loads and gather via ds_read_b128; else global fallback.
// LDS row stride 40 ushorts (80B) -> consecutive idx hit disjoint bank-quads.
template <int K>
__global__ __launch_bounds__(256) void conv_mfma_kernel(
    const unsigned short* __restrict__ x,   // [Nx][32] bf16
    const int* __restrict__ nbr,            // [K][N]
    const unsigned short* __restrict__ Wp,  // packed [K][2][64][8]
    unsigned short* __restrict__ y,         // [N][32] bf16
    float* __restrict__ part, int N)
{
    constexpr int XV     = (K == 27) ? 3 : 2;   // x-variants per group
    constexpr int GROUPS = (K == 27) ? 9 : 4;   // (dy,dz) groups
    constexpr int S      = GROUPS;              // tap stride between x-variants

    __shared__ __align__(16) unsigned short win[WROWS * 40];
    __shared__ float sm[64];
    __shared__ int wmm[2];

    const int nb = (N + 255) / 256;
    const int lb = xcd_swizzle(nb);
    const int lane = threadIdx.x & 63;
    const int wave = threadIdx.x >> 6;
    const int m = lane & 15, q = lane >> 4;
    const int rowbase = lb * 256 + wave * 64;
    const int r0 = rowbase + m, r1 = r0 + 16, r2 = r0 + 32, r3 = r0 + 48;
    const bool v0 = r0 < N, v1 = r1 < N, v2 = r2 < N, v3 = r3 < N;

    floatx4 c00 = {0.f, 0.f, 0.f, 0.f};
    floatx4 c01 = c00, c10 = c00, c11 = c00;
    floatx4 c20 = c00, c21 = c00, c30 = c00, c31 = c00;

#define IDX(k, rr, vv) ((vv) ? nbr[(size_t)(k) * N + (rr)] : -1)
#define LG(ii) ({ short8 z_ = {}; \
    (ii) >= 0 ? *(const short8*)(&win[((ii) - wmin) * 40 + q * 8]) : z_; })
#define PROC_TAP(A0, A1, A2, A3, tap)                         \
    {                                                         \
        const short8* wk = (const short8*)(Wp + (size_t)(tap) * 1024); \
        short8 b0 = wk[lane];                                 \
        short8 b1 = wk[64 + lane];                            \
        c00 = MFMA_BF16(A0, b0, c00, 0, 0, 0);                \
        c01 = MFMA_BF16(A0, b1, c01, 0, 0, 0);                \
        c10 = MFMA_BF16(A1, b0, c10, 0, 0, 0);                \
        c11 = MFMA_BF16(A1, b1, c11, 0, 0, 0);                \
        c20 = MFMA_BF16(A2, b0, c20, 0, 0, 0);                \
        c21 = MFMA_BF16(A2, b1, c21, 0, 0, 0);                \
        c30 = MFMA_BF16(A3, b0, c30, 0, 0, 0);                \
        c31 = MFMA_BF16(A3, b1, c31, 0, 0, 0);                \
    }

    for (int g = 0; g < GROUPS; ++g) {
        if (threadIdx.x == 0) { wmm[0] = 0x7fffffff; wmm[1] = -1; }
        __syncthreads();

        // indices for the XV taps of this group (named scalars only)
        int ia0 = IDX(g, r0, v0), ia1 = IDX(g, r1, v1);
        int ia2 = IDX(g, r2, v2), ia3 = IDX(g, r3, v3);
        int ib0 = IDX(g + S, r0, v0), ib1 = IDX(g + S, r1, v1);
        int ib2 = IDX(g + S, r2, v2), ib3 = IDX(g + S, r3, v3);
        int ic0 = -1, ic1 = -1, ic2 = -1, ic3 = -1;
        if (XV == 3) {
            ic0 = IDX(g + 2 * S, r0, v0); ic1 = IDX(g + 2 * S, r1, v1);
            ic2 = IDX(g + 2 * S, r2, v2); ic3 = IDX(g + 2 * S, r3, v3);
        }

        // block min/max of valid idx
#define MN(a) ((a) < 0 ? 0x7fffffff : (a))
        int lmin = min(min(min(MN(ia0), MN(ia1)), min(MN(ia2), MN(ia3))),
                       min(min(MN(ib0), MN(ib1)), min(MN(ib2), MN(ib3))));
        int lmax = max(max(max(ia0, ia1), max(ia2, ia3)),
                       max(max(ib0, ib1), max(ib2, ib3)));
        if (XV == 3) {
            lmin = min(lmin, min(min(MN(ic0), MN(ic1)), min(MN(ic2), MN(ic3))));
            lmax = max(lmax, max(max(ic0, ic1), max(ic2, ic3)));
        }
#undef MN
#pragma unroll
        for (int off = 32; off >= 1; off >>= 1) {
            lmin = min(lmin, __shfl_down(lmin, off));
            lmax = max(lmax, __shfl_down(lmax, off));
        }
        if (lane == 0) { atomicMin(&wmm[0], lmin); atomicMax(&wmm[1], lmax); }
        __syncthreads();

        const int wmin = wmm[0];
        const int wspan = wmm[1] - wmin + 1;     // wmm[1]==-1 -> negative
        const bool any = (wmm[1] >= 0);

        if (any && wspan <= WROWS) {             // block-uniform
            // stage window: coalesced 16B chunks, padded LDS row stride 80B
            const short8* src = (const short8*)(x + (size_t)wmin * 32);
            for (int c = threadIdx.x; c < wspan * 4; c += 256) {
                int rr = c >> 2, hh = c & 3;
                *(short8*)&win[rr * 40 + hh * 8] = src[c];
            }
            __syncthreads();
            {
                short8 a0 = LG(ia0), a1 = LG(ia1), a2 = LG(ia2), a3 = LG(ia3);
                PROC_TAP(a0, a1, a2, a3, g)
            }
            {
                short8 a0 = LG(ib0), a1 = LG(ib1), a2 = LG(ib2), a3 = LG(ib3);
                PROC_TAP(a0, a1, a2, a3, g + S)
            }
            if (XV == 3) {
                short8 a0 = LG(ic0), a1 = LG(ic1), a2 = LG(ic2), a3 = LG(ic3);
                PROC_TAP(a0, a1, a2, a3, g + 2 * S)
            }
        } else if (any) {                        // global-gather fallback
            {
                short8 a0 = gath(x, ia0, q), a1 = gath(x, ia1, q);
                short8 a2 = gath(x, ia2, q), a3 = gath(x, ia3, q);
                PROC_TAP(a0, a1, a2, a3, g)
            }
            {
                short8 a0 = gath(x, ib0, q), a1 = gath(x, ib1, q);
                short8 a2 = gath(x, ib2, q), a3 = gath(x, ib3, q);
                PROC_TAP(a0, a1, a2, a3, g + S)
            }
            if (XV == 3) {
                short8 a0 = gath(x, ic0, q), a1 = gath(x, ic1, q);
                short8 a2 = gath(x, ic2, q), a3 = gath(x, ic3, q);
                PROC_TAP(a0, a1, a2, a3, g + 2 * S)
            }
        }
        __syncthreads();   // win reads & wmm reads done before next group
    }
#undef IDX
#undef LG
#undef PROC_TAP

    // epilogue: stores (C-layout: col = lane&15, row-in-tile = q*4+r) + stats
    if (threadIdx.x < 64) sm[threadIdx.x] = 0.f;
    __syncthreads();

#define STORE2(cA, cB, tb)                                        \
    _Pragma("unroll")                                             \
    for (int r = 0; r < 4; ++r) {                                 \
        int ra = rowbase + (tb) * 16 + q * 4 + r;                 \
        if (ra < N) {                                             \
            y[(size_t)ra * 32 + m]      = f2bf(cA[r]);            \
            y[(size_t)ra * 32 + 16 + m] = f2bf(cB[r]);            \
        }                                                         \
    }
    STORE2(c00, c01, 0) STORE2(c10, c11, 1) STORE2(c20, c21, 2) STORE2(c30, c31, 3)
#undef STORE2

    float s0 = 0.f, q0 = 0.f, s1 = 0.f, q1 = 0.f;
#pragma unroll
    for (int r = 0; r < 4; ++r) {
        s0 += c00[r] + c10[r] + c20[r] + c30[r];
        q0 += c00[r] * c00[r] + c10[r] * c10[r] + c20[r] * c20[r] + c30[r] * c30[r];
        s1 += c01[r] + c11[r] + c21[r] + c31[r];
        q1 += c01[r] * c01[r] + c11[r] * c11[r] + c21[r] * c21[r] + c31[r] * c31[r];
    }
    s0 += __shfl_down(s0, 32); s0 += __shfl_down(s0, 16);
    q0 += __shfl_down(q0, 32); q0 += __shfl_down(q0, 16);
    s1 += __shfl_down(s1, 32); s1 += __shfl_down(s1, 16);
    q1 += __shfl_down(q1, 32); q1 += __shfl_down(q1, 16);
    if (lane < 16) {
        atomicAdd(&sm[m],      s0);
        atomicAdd(&sm[32 + m], q0);
        atomicAdd(&sm[16 + m],      s1);
        atomicAdd(&sm[48 + m], q1);
    }
    __syncthreads();
    if (threadIdx.x < 64)
        part[(size_t)lb * 64 + threadIdx.x] = sm[threadIdx.x];
}

// ---------------------------------------------------------------------------
// stem1 as MFMA: CI=4, 27 taps folded into kdim = tap*4+ci, 4 chunks of K=32.
__global__ __launch_bounds__(256) void conv_stem1_mfma(
    const unsigned short* __restrict__ xb,  // [N][4] bf16
    const int* __restrict__ nbr,            // [27][N]
    const unsigned short* __restrict__ Wp,  // packed [4][2][64][8]
    unsigned short* __restrict__ y,         // [N][32] bf16
    float* __restrict__ part, int N)
{
    __shared__ float sm[64];
    const int nb = (N + 127) / 128;
    const int lb = xcd_swizzle(nb);
    const int lane = threadIdx.x & 63;
    const int wave = threadIdx.x >> 6;
    const int m = lane & 15, q = lane >> 4;
    const int rowbase = lb * 128 + wave * 32;
    const int row0 = rowbase + m;
    const int row1 = rowbase + 16 + m;

    floatx4 acc00 = {0.f, 0.f, 0.f, 0.f};
    floatx4 acc01 = acc00, acc10 = acc00, acc11 = acc00;

#pragma unroll
    for (int c = 0; c < 4; ++c) {
        const int t0 = c * 8 + q * 2, t1 = t0 + 1;
        short8 a0 = {}, a1 = {};
        {
            int ia = (t0 < 27 && row0 < N) ? nbr[(size_t)t0 * N + row0] : -1;
            int ib = (t1 < 27 && row0 < N) ? nbr[(size_t)t1 * N + row0] : -1;
            ushortv4 ga = {}, gb = {};
            if (ia >= 0) ga = *(const ushortv4*)(xb + (size_t)ia * 4);
            if (ib >= 0) gb = *(const ushortv4*)(xb + (size_t)ib * 4);
            a0[0] = (short)ga[0]; a0[1] = (short)ga[1];
            a0[2] = (short)ga[2]; a0[3] = (short)ga[3];
            a0[4] = (short)gb[0]; a0[5] = (short)gb[1];
            a0[6] = (short)gb[2]; a0[7] = (short)gb[3];
        }
        {
            int ia = (t0 < 27 && row1 < N) ? nbr[(size_t)t0 * N + row1] : -1;
            int ib = (t1 < 27 && row1 < N) ? nbr[(size_t)t1 * N + row1] : -1;
            ushortv4 ga = {}, gb = {};
            if (ia >= 0) ga = *(const ushortv4*)(xb + (size_t)ia * 4);
            if (ib >= 0) gb = *(const ushortv4*)(xb + (size_t)ib * 4);
            a1[0] = (short)ga[0]; a1[1] = (short)ga[1];
            a1[2] = (short)ga[2]; a1[3] = (short)ga[3];
            a1[4] = (short)gb[0]; a1[5] = (short)gb[1];
            a1[6] = (short)gb[2]; a1[7] = (short)gb[3];
        }
        const short8* wk = (const short8*)Wp;
        short8 b0 = wk[(c * 2 + 0) * 64 + lane];
        short8 b1 = wk[(c * 2 + 1) * 64 + lane];
        acc00 = MFMA_BF16(a0, b0, acc00, 0, 0, 0);
        acc01 = MFMA_BF16(a0, b1, acc01, 0, 0, 0);
        acc10 = MFMA_BF16(a1, b0, acc10, 0, 0, 0);
        acc11 = MFMA_BF16(a1, b1, acc11, 0, 0, 0);
    }

    conv_epilogue2(acc00, acc01, acc10, acc11, y, part, rowbase, lb, N, sm);
}

// ---------------------------------------------------------------------------
// Parallel stat reduction: part[nb][64] -> atomicAdd into stats[64] (pre-zeroed).
__global__ __launch_bounds__(256) void reduce_stats_kernel(
    const float* __restrict__ part, float* __restrict__ stats, int nb)
{
    __shared__ float sm[256];
    int t = threadIdx.x;
    int c = t & 63, g = t >> 6;
    float s = 0.f;
    for (int b = blockIdx.x * 4 + g; b < nb; b += 256)
        s += part[(size_t)b * 64 + c];
    sm[t] = s;
    __syncthreads();
    if (t < 64)
        atomicAdd(&stats[t], sm[t] + sm[64 + t] + sm[128 + t] + sm[192 + t]);
}

// ---------------------------------------------------------------------------
// BN (+optional bf16 residual) + ReLU. bf16 in; bf16 or fp32 out.
template <bool OUT_F32, bool HAS_RES>
__global__ __launch_bounds__(256) void bn_relu_kernel(
    const unsigned short* __restrict__ y, const float* __restrict__ stats,
    const float* __restrict__ gamma, const float* __restrict__ beta,
    const unsigned short* __restrict__ resid, void* __restrict__ outp, int N)
{
    int t = blockIdx.x * 256 + threadIdx.x;
    if (t >= N) return;
    float inv_n = 1.0f / (float)N;
    const ushort8* yr = (const ushort8*)(y + (size_t)t * 32);

#pragma unroll
    for (int c = 0; c < 4; ++c) {
        ushort8 v = yr[c];
        ushort8 rv = {};
        if (HAS_RES) rv = ((const ushort8*)(resid + (size_t)t * 32))[c];
        float f0, f1, f2, f3, f4, f5, f6, f7;
#define BNJ(fj, j)                                                        \
        {                                                                 \
            int co = c * 8 + (j);                                         \
            float mu = stats[co] * inv_n;                                 \
            float var = stats[32 + co] * inv_n - mu * mu;                 \
            float sc = rsqrtf(var + EPS) * gamma[co];                     \
            fj = (bf2f(v[j]) - mu) * sc + beta[co];                       \
            if (HAS_RES) fj += bf2f(rv[j]);                               \
            fj = fmaxf(fj, 0.0f);                                         \
        }
        BNJ(f0, 0) BNJ(f1, 1) BNJ(f2, 2) BNJ(f3, 3)
        BNJ(f4, 4) BNJ(f5, 5) BNJ(f6, 6) BNJ(f7, 7)
#undef BNJ
        if (OUT_F32) {
            float* ob = (float*)outp + (size_t)t * 32 + c * 8;
            floatx4 u0 = {f0, f1, f2, f3}, u1 = {f4, f5, f6, f7};
            *(floatx4*)(ob) = u0;
            *(floatx4*)(ob + 4) = u1;
        } else {
            ushort8 o;
            o[0] = f2bf(f0); o[1] = f2bf(f1); o[2] = f2bf(f2); o[3] = f2bf(f3);
            o[4] = f2bf(f4); o[5] = f2bf(f5); o[6] = f2bf(f6); o[7] = f2bf(f7);
            ((ushort8*)((unsigned short*)outp + (size_t)t * 32))[c] = o;
        }
    }
}

// ---------------------------------------------------------------------------
extern "C" void kernel_launch(void* const* d_in, const int* in_sizes, int n_in,
                              void* d_out, int out_size, void* d_ws, size_t ws_size,
                              hipStream_t stream)
{
    const float* vf   = (const float*)d_in[0];
    const float* Ws1  = (const float*)d_in[1];
    const float* Ws2  = (const float*)d_in[2];
    const float* Wd   = (const float*)d_in[3];
    const float* Wr1a = (const float*)d_in[4];
    const float* Wr1b = (const float*)d_in[5];
    const float* Wr2a = (const float*)d_in[6];
    const float* Wr2b = (const float*)d_in[7];
    const float* gam  = (const float*)d_in[8];
    const float* bet  = (const float*)d_in[9];
    const int* nbr0   = (const int*)d_in[10];
    const int* down1  = (const int*)d_in[11];
    const int* nbr1   = (const int*)d_in[12];

    int N0 = in_sizes[0] / 4;
    int N1 = in_sizes[11] / 8;

    // ws layout (bf16 buffers as unsigned short)
    unsigned short* yraw = (unsigned short*)d_ws;            // N0*32
    unsigned short* actA = yraw + (size_t)N0 * 32;           // N0*32
    unsigned short* actB = actA + (size_t)N0 * 32;           // N0*32
    unsigned short* xb   = actB + (size_t)N0 * 32;           // N0*4
    unsigned short* wp   = xb + (size_t)N0 * 4;              // packed weights
    float* part  = (float*)(wp + WP_TOTAL);                  // <=3200 blocks * 64
    float* stats = part + (size_t)3200 * 64;                 // 7*64 fp32

    hipMemsetAsync(stats, 0, 7 * 64 * sizeof(float), stream);

    auto g1 = [](int n) { return dim3((unsigned)((n + 255) / 256)); };
    auto gm = [](int n) { return dim3((unsigned)((n + 255) / 256)); };   // 256 rows/block
    auto gs = [](int n) { return dim3((unsigned)((n + 127) / 128)); };   // stem1: 128 rows/block
    int nbs1 = (N0 + 127) / 128;                 // stem1 partial count
    int nb0 = (N0 + 255) / 256;                  // CI=32 conv partial counts
    int nb1 = (N1 + 255) / 256;

    int prep_threads = N0 + 512 + 128 * (27 * 5 + 8);
    prep_kernel<<<g1(prep_threads), 256, 0, stream>>>(
        vf, Ws1, Ws2, Wd, Wr1a, Wr1b, Wr2a, Wr2b, xb, wp, N0);

    // stem1: xb -> yraw; act -> actA
    conv_stem1_mfma<<<gs(N0), 256, 0, stream>>>(xb, nbr0, wp + O_S1, yraw, part, N0);
    reduce_stats_kernel<<<64, 256, 0, stream>>>(part, stats + 0 * 64, nbs1);
    bn_relu_kernel<false, false><<<g1(N0), 256, 0, stream>>>(yraw, stats + 0 * 64, gam + 0, bet + 0, nullptr, actA, N0);
    // stem2: actA -> yraw; act -> actB
    conv_mfma_kernel<27><<<gm(N0), 256, 0, stream>>>(actA, nbr0, wp + O_S2, yraw, part, N0);
    reduce_stats_kernel<<<64, 256, 0, stream>>>(part, stats + 1 * 64, nb0);
    bn_relu_kernel<false, false><<<g1(N0), 256, 0, stream>>>(yraw, stats + 1 * 64, gam + 32, bet + 32, nullptr, actB, N0);
    // down: actB (N0 rows) -> yraw (N1); x1 -> actA
    conv_mfma_kernel<8><<<gm(N1), 256, 0, stream>>>(actB, down1, wp + O_DN, yraw, part, N1);
    reduce_stats_kernel<<<64, 256, 0, stream>>>(part, stats + 2 * 64, nb1);
    bn_relu_kernel<false, false><<<g1(N1), 256, 0, stream>>>(yraw, stats + 2 * 64, gam + 64, bet + 64, nullptr, actA, N1);
    // r1a: actA -> yraw; h -> actB
    conv_mfma_kernel<27><<<gm(N1), 256, 0, stream>>>(actA, nbr1, wp + O_R1A, yraw, part, N1);
    reduce_stats_kernel<<<64, 256, 0, stream>>>(part, stats + 3 * 64, nb1);
    bn_relu_kernel<false, false><<<g1(N1), 256, 0, stream>>>(yraw, stats + 3 * 64, gam + 96, bet + 96, nullptr, actB, N1);
    // r1b: actB -> yraw; x1' = relu(bn(yraw) + actA) -> actB
    conv_mfma_kernel<27><<<gm(N1), 256, 0, stream>>>(actB, nbr1, wp + O_R1B, yraw, part, N1);
    reduce_stats_kernel<<<64, 256, 0, stream>>>(part, stats + 4 * 64, nb1);
    bn_relu_kernel<false, true><<<g1(N1), 256, 0, stream>>>(yraw, stats + 4 * 64, gam + 128, bet + 128, actA, actB, N1);
    // r2a: actB -> yraw; h2 -> actA
    conv_mfma_kernel<27><<<gm(N1), 256, 0, stream>>>(actB, nbr1, wp + O_R2A, yraw, part, N1);
    reduce_stats_kernel<<<64, 256, 0, stream>>>(part, stats + 5 * 64, nb1);
    bn_relu_kernel<false, false><<<g1(N1), 256, 0, stream>>>(yraw, stats + 5 * 64, gam + 160, bet + 160, nullptr, actA, N1);
    // r2b: actA -> yraw; out = relu(bn(yraw) + actB) -> d_out (fp32)
    conv_mfma_kernel<27><<<gm(N1), 256, 0, stream>>>(actA, nbr1, wp + O_R2B, yraw, part, N1);
    reduce_stats_kernel<<<64, 256, 0, stream>>>(part, stats + 6 * 64, nb1);
    bn_relu_kernel<true, true><<<g1(N1), 256, 0, stream>>>(yraw, stats + 6 * 64, gam + 192, bet + 192, actB, d_out, N1);
}

// Round 11
// 632.022 us; speedup vs baseline: 1.1336x; 1.1336x over previous
//
#include <hip/hip_runtime.h>

#define EPS 1e-5f
#define WROWS 448   // LDS window rows; 448*80B = 35.8KB -> 4 blocks/CU

typedef __attribute__((ext_vector_type(8))) short short8;            // 8 bf16 MFMA frag
typedef __attribute__((ext_vector_type(4))) float floatx4;           // MFMA C/D frag
typedef __attribute__((ext_vector_type(8))) unsigned short ushort8;
typedef __attribute__((ext_vector_type(4))) unsigned short ushortv4;

// packed-weight element offsets (compile-time)
#define O_S1  0
#define O_S2  4096
#define O_DN  (O_S2 + 27648)
#define O_R1A (O_DN + 8192)
#define O_R1B (O_R1A + 27648)
#define O_R2A (O_R1B + 27648)
#define O_R2B (O_R2A + 27648)
#define WP_TOTAL (O_R2B + 27648)

// bf16 <-> f32 (RTNE)
__device__ __forceinline__ unsigned short f2bf(float f) {
    union { float f; unsigned u; } x; x.f = f;
    unsigned r = x.u + 0x7fffu + ((x.u >> 16) & 1u);
    return (unsigned short)(r >> 16);
}
__device__ __forceinline__ float bf2f(unsigned short b) {
    union { unsigned u; float f; } x; x.u = ((unsigned)b) << 16;
    return x.f;
}

// XCD-aware block remap [R8: halved FETCH]; contiguous spans also keep the
// per-group windows small for LDS staging.
__device__ __forceinline__ int xcd_swizzle(int nb) {
    int b = (int)blockIdx.x;
    int q = nb >> 3, r = nb & 7;
    int x = b & 7, i = b >> 3;
    return x * q + (x < r ? x : r) + i;
}

// guarded 16B A-fragment gather from GLOBAL (fallback path)
__device__ __forceinline__ short8 gath(const unsigned short* __restrict__ x,
                                       int ii, int q) {
    short8 z = {};
    return (ii >= 0) ? *(const short8*)(x + (size_t)ii * 32 + q * 8) : z;
}

// ---------------------------------------------------------------------------
// One fused prep launch: cvt vf->bf16, pack stem1 W, pack six CI=32 W sets.
__device__ __forceinline__ void pack_w_one(
    const float* __restrict__ W, unsigned short* __restrict__ out, int t)
{
    int lane = t & 63;
    int h = (t >> 6) & 1;
    int k = t >> 7;
    int m = lane & 15, q = lane >> 4;
    ushort8 v;
#pragma unroll
    for (int j = 0; j < 8; ++j)
        v[j] = f2bf(W[((size_t)k * 32 + q * 8 + j) * 32 + h * 16 + m]);
    *(ushort8*)(out + (size_t)t * 8) = v;
}

__global__ __launch_bounds__(256) void prep_kernel(
    const float* __restrict__ vf,
    const float* __restrict__ Ws1, const float* __restrict__ Ws2,
    const float* __restrict__ Wd,  const float* __restrict__ Wr1a,
    const float* __restrict__ Wr1b, const float* __restrict__ Wr2a,
    const float* __restrict__ Wr2b,
    unsigned short* __restrict__ xb, unsigned short* __restrict__ wp, int N0)
{
    int t = blockIdx.x * 256 + threadIdx.x;
    if (t < N0) {                                   // cvt vf -> bf16
        float4 v = *(const float4*)(vf + (size_t)t * 4);
        ushortv4 r = {f2bf(v.x), f2bf(v.y), f2bf(v.z), f2bf(v.w)};
        *(ushortv4*)(xb + (size_t)t * 4) = r;
        return;
    }
    t -= N0;
    if (t < 512) {                                  // stem1 pack (taps folded into K)
        int lane = t & 63;
        int h = (t >> 6) & 1;
        int c = t >> 7;
        int m = lane & 15, q = lane >> 4;
        ushort8 v;
#pragma unroll
        for (int j = 0; j < 8; ++j) {
            int kdim = c * 32 + q * 8 + j;
            int tap = kdim >> 2, ci = kdim & 3;
            v[j] = (tap < 27) ? f2bf(Ws1[((size_t)tap * 4 + ci) * 32 + h * 16 + m]) : 0;
        }
        *(ushort8*)(wp + O_S1 + (size_t)t * 8) = v;
        return;
    }
    t -= 512;
    if (t < 27 * 128) { pack_w_one(Ws2,  wp + O_S2,  t); return; }
    t -= 27 * 128;
    if (t < 8 * 128)  { pack_w_one(Wd,   wp + O_DN,  t); return; }
    t -= 8 * 128;
    if (t < 27 * 128) { pack_w_one(Wr1a, wp + O_R1A, t); return; }
    t -= 27 * 128;
    if (t < 27 * 128) { pack_w_one(Wr1b, wp + O_R1B, t); return; }
    t -= 27 * 128;
    if (t < 27 * 128) { pack_w_one(Wr2a, wp + O_R2A, t); return; }
    t -= 27 * 128;
    if (t < 27 * 128) { pack_w_one(Wr2b, wp + O_R2B, t); return; }
}

// ---------------------------------------------------------------------------
// Epilogue (2-tile): C-layout stores + BN partials -> LDS -> part[lb].
__device__ __forceinline__ void conv_epilogue2(
    floatx4 acc00, floatx4 acc01, floatx4 acc10, floatx4 acc11,
    unsigned short* __restrict__ y, float* __restrict__ part,
    int rowbase, int lb, int N, float* sm)
{
    const int lane = threadIdx.x & 63;
    const int m = lane & 15, q = lane >> 4;

    if (threadIdx.x < 64) sm[threadIdx.x] = 0.f;
    __syncthreads();

#pragma unroll
    for (int r = 0; r < 4; ++r) {
        int ra = rowbase + q * 4 + r;
        int rb = ra + 16;
        if (ra < N) {
            y[(size_t)ra * 32 + m]      = f2bf(acc00[r]);
            y[(size_t)ra * 32 + 16 + m] = f2bf(acc01[r]);
        }
        if (rb < N) {
            y[(size_t)rb * 32 + m]      = f2bf(acc10[r]);
            y[(size_t)rb * 32 + 16 + m] = f2bf(acc11[r]);
        }
    }

    float s0 = 0.f, q0 = 0.f, s1 = 0.f, q1 = 0.f;
#pragma unroll
    for (int r = 0; r < 4; ++r) {
        s0 += acc00[r] + acc10[r];
        q0 += acc00[r] * acc00[r] + acc10[r] * acc10[r];
        s1 += acc01[r] + acc11[r];
        q1 += acc01[r] * acc01[r] + acc11[r] * acc11[r];
    }
    s0 += __shfl_down(s0, 32); s0 += __shfl_down(s0, 16);
    q0 += __shfl_down(q0, 32); q0 += __shfl_down(q0, 16);
    s1 += __shfl_down(s1, 32); s1 += __shfl_down(s1, 16);
    q1 += __shfl_down(q1, 32); q1 += __shfl_down(q1, 16);
    if (lane < 16) {
        atomicAdd(&sm[m],      s0);
        atomicAdd(&sm[32 + m], q0);
        atomicAdd(&sm[16 + m],      s1);
        atomicAdd(&sm[48 + m], q1);
    }
    __syncthreads();
    if (threadIdx.x < 64)
        part[(size_t)lb * 64 + threadIdx.x] = sm[threadIdx.x];
}

#define MFMA_BF16 __builtin_amdgcn_mfma_f32_16x16x32_bf16

// ---------------------------------------------------------------------------
// MFMA sparse conv with dz-grouped LDS window staging (round 11).
// Tap order (ref _offsets): tap = (dx+1)*9 + (dy+1)*3 + (dz+1) for K=27
// (z fastest), tap = dx*4 + dy*2 + dz for K=8. Group by dz: K=27 -> 3 groups
// of 9 taps {c+3j}; K=8 -> 2 groups of 4 taps {c+2j}. The window for fixed dz
// is one z-plane's y/x-neighborhood: contiguous, span ~150-400 rows per
// 128-row block. Stage once per group (amortized over TPG taps -> R10's 9
// stagings become <=3), ds_read_b128 gathers replace TA-serialized global
// gathers. 2 barriers/group (wmm slots pre-initialized once).
// [R9/R10 evidence: TA-addr-bound; R10's win was eaten by 9 stagings + 36
//  barriers + butterflies — fixed here.]
template <int K>
__global__ __launch_bounds__(256) void conv_mfma_kernel(
    const unsigned short* __restrict__ x,   // [Nx][32] bf16
    const int* __restrict__ nbr,            // [K][N]
    const unsigned short* __restrict__ Wp,  // packed [K][2][64][8]
    unsigned short* __restrict__ y,         // [N][32] bf16
    float* __restrict__ part, int N)
{
    constexpr int ZG  = (K == 27) ? 3 : 2;   // dz groups
    constexpr int TPG = (K == 27) ? 9 : 4;   // taps per group

    __shared__ __align__(16) unsigned short win[WROWS * 40];
    __shared__ float sm[64];
    __shared__ int wmm[2 * 3];

    const int nb = (N + 127) / 128;
    const int lb = xcd_swizzle(nb);
    const int lane = threadIdx.x & 63;
    const int wave = threadIdx.x >> 6;
    const int m = lane & 15, q = lane >> 4;
    const int rowbase = lb * 128 + wave * 32;
    const int r0 = rowbase + m;
    const int r1 = r0 + 16;
    const bool v0 = r0 < N, v1 = r1 < N;

    floatx4 c00 = {0.f, 0.f, 0.f, 0.f};
    floatx4 c01 = c00, c10 = c00, c11 = c00;

    if (threadIdx.x < 2 * ZG)
        wmm[threadIdx.x] = (threadIdx.x & 1) ? -1 : 0x7fffffff;
    __syncthreads();

#define IDX(k, rr, vv) ((vv) ? nbr[(size_t)(k) * N + (rr)] : -1)
#define LG(ii) ({ short8 z_ = {}; \
    (ii) >= 0 ? *(const short8*)(&win[((ii) - wmin) * 40 + q * 8]) : z_; })
#define MN(a) ((a) < 0 ? 0x7fffffff : (a))

    for (int c = 0; c < ZG; ++c) {
        // idx loads for all TPG taps (named scalars; unused slots fold to -1)
        int ia0 = (0 < TPG) ? IDX(c + ZG * 0, r0, v0) : -1;
        int ib0 = (0 < TPG) ? IDX(c + ZG * 0, r1, v1) : -1;
        int ia1 = (1 < TPG) ? IDX(c + ZG * 1, r0, v0) : -1;
        int ib1 = (1 < TPG) ? IDX(c + ZG * 1, r1, v1) : -1;
        int ia2 = (2 < TPG) ? IDX(c + ZG * 2, r0, v0) : -1;
        int ib2 = (2 < TPG) ? IDX(c + ZG * 2, r1, v1) : -1;
        int ia3 = (3 < TPG) ? IDX(c + ZG * 3, r0, v0) : -1;
        int ib3 = (3 < TPG) ? IDX(c + ZG * 3, r1, v1) : -1;
        int ia4 = (4 < TPG) ? IDX(c + ZG * 4, r0, v0) : -1;
        int ib4 = (4 < TPG) ? IDX(c + ZG * 4, r1, v1) : -1;
        int ia5 = (5 < TPG) ? IDX(c + ZG * 5, r0, v0) : -1;
        int ib5 = (5 < TPG) ? IDX(c + ZG * 5, r1, v1) : -1;
        int ia6 = (6 < TPG) ? IDX(c + ZG * 6, r0, v0) : -1;
        int ib6 = (6 < TPG) ? IDX(c + ZG * 6, r1, v1) : -1;
        int ia7 = (7 < TPG) ? IDX(c + ZG * 7, r0, v0) : -1;
        int ib7 = (7 < TPG) ? IDX(c + ZG * 7, r1, v1) : -1;
        int ia8 = (8 < TPG) ? IDX(c + ZG * 8, r0, v0) : -1;
        int ib8 = (8 < TPG) ? IDX(c + ZG * 8, r1, v1) : -1;

        int lmin = min(min(min(min(MN(ia0), MN(ib0)), min(MN(ia1), MN(ib1))),
                           min(min(MN(ia2), MN(ib2)), min(MN(ia3), MN(ib3)))),
                       min(min(min(MN(ia4), MN(ib4)), min(MN(ia5), MN(ib5))),
                           min(min(MN(ia6), MN(ib6)),
                               min(min(MN(ia7), MN(ib7)), min(MN(ia8), MN(ib8))))));
        int lmax = max(max(max(max(ia0, ib0), max(ia1, ib1)),
                           max(max(ia2, ib2), max(ia3, ib3))),
                       max(max(max(ia4, ib4), max(ia5, ib5)),
                           max(max(ia6, ib6), max(max(ia7, ib7), max(ia8, ib8)))));
#pragma unroll
        for (int off = 32; off >= 1; off >>= 1) {
            lmin = min(lmin, __shfl_down(lmin, off));
            lmax = max(lmax, __shfl_down(lmax, off));
        }
        if (lane == 0) { atomicMin(&wmm[2 * c], lmin); atomicMax(&wmm[2 * c + 1], lmax); }
        __syncthreads();   // wmm ready; also: every wave finished group c-1 compute

        const int wmin = wmm[2 * c];
        const int wmax = wmm[2 * c + 1];
        const bool any = (wmax >= 0);
        const int wspan = wmax - wmin + 1;
        const bool use_lds = any && (wspan <= WROWS);   // block-uniform

        if (use_lds) {
            const short8* src = (const short8*)(x + (size_t)wmin * 32);
            for (int cc = threadIdx.x; cc < wspan * 4; cc += 256) {
                int rr = cc >> 2, hh = cc & 3;
                *(short8*)&win[rr * 40 + hh * 8] = src[cc];
            }
        }
        __syncthreads();   // window staged (no-op ordering for fallback)

#define TAPC(J, iA, iB)                                                   \
        if (J < TPG) {                                                    \
            const short8* wk = (const short8*)(Wp + (size_t)(c + ZG * J) * 1024); \
            short8 b0 = wk[lane];                                         \
            short8 b1 = wk[64 + lane];                                    \
            short8 a0, a1;                                                \
            if (use_lds) { a0 = LG(iA); a1 = LG(iB); }                    \
            else         { a0 = gath(x, iA, q); a1 = gath(x, iB, q); }    \
            c00 = MFMA_BF16(a0, b0, c00, 0, 0, 0);                        \
            c01 = MFMA_BF16(a0, b1, c01, 0, 0, 0);                        \
            c10 = MFMA_BF16(a1, b0, c10, 0, 0, 0);                        \
            c11 = MFMA_BF16(a1, b1, c11, 0, 0, 0);                        \
        }
        if (any) {
            TAPC(0, ia0, ib0) TAPC(1, ia1, ib1) TAPC(2, ia2, ib2)
            TAPC(3, ia3, ib3) TAPC(4, ia4, ib4) TAPC(5, ia5, ib5)
            TAPC(6, ia6, ib6) TAPC(7, ia7, ib7) TAPC(8, ia8, ib8)
        }
#undef TAPC
    }
#undef IDX
#undef LG
#undef MN

    conv_epilogue2(c00, c01, c10, c11, y, part, rowbase, lb, N, sm);
}

// ---------------------------------------------------------------------------
// stem1 as MFMA: CI=4, 27 taps folded into kdim = tap*4+ci, 4 chunks of K=32.
__global__ __launch_bounds__(256) void conv_stem1_mfma(
    const unsigned short* __restrict__ xb,  // [N][4] bf16
    const int* __restrict__ nbr,            // [27][N]
    const unsigned short* __restrict__ Wp,  // packed [4][2][64][8]
    unsigned short* __restrict__ y,         // [N][32] bf16
    float* __restrict__ part, int N)
{
    __shared__ float sm[64];
    const int nb = (N + 127) / 128;
    const int lb = xcd_swizzle(nb);
    const int lane = threadIdx.x & 63;
    const int wave = threadIdx.x >> 6;
    const int m = lane & 15, q = lane >> 4;
    const int rowbase = lb * 128 + wave * 32;
    const int row0 = rowbase + m;
    const int row1 = rowbase + 16 + m;

    floatx4 acc00 = {0.f, 0.f, 0.f, 0.f};
    floatx4 acc01 = acc00, acc10 = acc00, acc11 = acc00;

#pragma unroll
    for (int c = 0; c < 4; ++c) {
        const int t0 = c * 8 + q * 2, t1 = t0 + 1;
        short8 a0 = {}, a1 = {};
        {
            int ia = (t0 < 27 && row0 < N) ? nbr[(size_t)t0 * N + row0] : -1;
            int ib = (t1 < 27 && row0 < N) ? nbr[(size_t)t1 * N + row0] : -1;
            ushortv4 ga = {}, gb = {};
            if (ia >= 0) ga = *(const ushortv4*)(xb + (size_t)ia * 4);
            if (ib >= 0) gb = *(const ushortv4*)(xb + (size_t)ib * 4);
            a0[0] = (short)ga[0]; a0[1] = (short)ga[1];
            a0[2] = (short)ga[2]; a0[3] = (short)ga[3];
            a0[4] = (short)gb[0]; a0[5] = (short)gb[1];
            a0[6] = (short)gb[2]; a0[7] = (short)gb[3];
        }
        {
            int ia = (t0 < 27 && row1 < N) ? nbr[(size_t)t0 * N + row1] : -1;
            int ib = (t1 < 27 && row1 < N) ? nbr[(size_t)t1 * N + row1] : -1;
            ushortv4 ga = {}, gb = {};
            if (ia >= 0) ga = *(const ushortv4*)(xb + (size_t)ia * 4);
            if (ib >= 0) gb = *(const ushortv4*)(xb + (size_t)ib * 4);
            a1[0] = (short)ga[0]; a1[1] = (short)ga[1];
            a1[2] = (short)ga[2]; a1[3] = (short)ga[3];
            a1[4] = (short)gb[0]; a1[5] = (short)gb[1];
            a1[6] = (short)gb[2]; a1[7] = (short)gb[3];
        }
        const short8* wk = (const short8*)Wp;
        short8 b0 = wk[(c * 2 + 0) * 64 + lane];
        short8 b1 = wk[(c * 2 + 1) * 64 + lane];
        acc00 = MFMA_BF16(a0, b0, acc00, 0, 0, 0);
        acc01 = MFMA_BF16(a0, b1, acc01, 0, 0, 0);
        acc10 = MFMA_BF16(a1, b0, acc10, 0, 0, 0);
        acc11 = MFMA_BF16(a1, b1, acc11, 0, 0, 0);
    }

    conv_epilogue2(acc00, acc01, acc10, acc11, y, part, rowbase, lb, N, sm);
}

// ---------------------------------------------------------------------------
// Parallel stat reduction: part[nb][64] -> atomicAdd into stats[64] (pre-zeroed).
__global__ __launch_bounds__(256) void reduce_stats_kernel(
    const float* __restrict__ part, float* __restrict__ stats, int nb)
{
    __shared__ float sm[256];
    int t = threadIdx.x;
    int c = t & 63, g = t >> 6;
    float s = 0.f;
    for (int b = blockIdx.x * 4 + g; b < nb; b += 256)
        s += part[(size_t)b * 64 + c];
    sm[t] = s;
    __syncthreads();
    if (t < 64)
        atomicAdd(&stats[t], sm[t] + sm[64 + t] + sm[128 + t] + sm[192 + t]);
}

// ---------------------------------------------------------------------------
// BN (+optional bf16 residual) + ReLU. bf16 in; bf16 or fp32 out.
template <bool OUT_F32, bool HAS_RES>
__global__ __launch_bounds__(256) void bn_relu_kernel(
    const unsigned short* __restrict__ y, const float* __restrict__ stats,
    const float* __restrict__ gamma, const float* __restrict__ beta,
    const unsigned short* __restrict__ resid, void* __restrict__ outp, int N)
{
    int t = blockIdx.x * 256 + threadIdx.x;
    if (t >= N) return;
    float inv_n = 1.0f / (float)N;
    const ushort8* yr = (const ushort8*)(y + (size_t)t * 32);

#pragma unroll
    for (int c = 0; c < 4; ++c) {
        ushort8 v = yr[c];
        ushort8 rv = {};
        if (HAS_RES) rv = ((const ushort8*)(resid + (size_t)t * 32))[c];
        float f0, f1, f2, f3, f4, f5, f6, f7;
#define BNJ(fj, j)                                                        \
        {                                                                 \
            int co = c * 8 + (j);                                         \
            float mu = stats[co] * inv_n;                                 \
            float var = stats[32 + co] * inv_n - mu * mu;                 \
            float sc = rsqrtf(var + EPS) * gamma[co];                     \
            fj = (bf2f(v[j]) - mu) * sc + beta[co];                       \
            if (HAS_RES) fj += bf2f(rv[j]);                               \
            fj = fmaxf(fj, 0.0f);                                         \
        }
        BNJ(f0, 0) BNJ(f1, 1) BNJ(f2, 2) BNJ(f3, 3)
        BNJ(f4, 4) BNJ(f5, 5) BNJ(f6, 6) BNJ(f7, 7)
#undef BNJ
        if (OUT_F32) {
            float* ob = (float*)outp + (size_t)t * 32 + c * 8;
            floatx4 u0 = {f0, f1, f2, f3}, u1 = {f4, f5, f6, f7};
            *(floatx4*)(ob) = u0;
            *(floatx4*)(ob + 4) = u1;
        } else {
            ushort8 o;
            o[0] = f2bf(f0); o[1] = f2bf(f1); o[2] = f2bf(f2); o[3] = f2bf(f3);
            o[4] = f2bf(f4); o[5] = f2bf(f5); o[6] = f2bf(f6); o[7] = f2bf(f7);
            ((ushort8*)((unsigned short*)outp + (size_t)t * 32))[c] = o;
        }
    }
}

// ---------------------------------------------------------------------------
extern "C" void kernel_launch(void* const* d_in, const int* in_sizes, int n_in,
                              void* d_out, int out_size, void* d_ws, size_t ws_size,
                              hipStream_t stream)
{
    const float* vf   = (const float*)d_in[0];
    const float* Ws1  = (const float*)d_in[1];
    const float* Ws2  = (const float*)d_in[2];
    const float* Wd   = (const float*)d_in[3];
    const float* Wr1a = (const float*)d_in[4];
    const float* Wr1b = (const float*)d_in[5];
    const float* Wr2a = (const float*)d_in[6];
    const float* Wr2b = (const float*)d_in[7];
    const float* gam  = (const float*)d_in[8];
    const float* bet  = (const float*)d_in[9];
    const int* nbr0   = (const int*)d_in[10];
    const int* down1  = (const int*)d_in[11];
    const int* nbr1   = (const int*)d_in[12];

    int N0 = in_sizes[0] / 4;
    int N1 = in_sizes[11] / 8;

    // ws layout (bf16 buffers as unsigned short)
    unsigned short* yraw = (unsigned short*)d_ws;            // N0*32
    unsigned short* actA = yraw + (size_t)N0 * 32;           // N0*32
    unsigned short* actB = actA + (size_t)N0 * 32;           // N0*32
    unsigned short* xb   = actB + (size_t)N0 * 32;           // N0*4
    unsigned short* wp   = xb + (size_t)N0 * 4;              // packed weights
    float* part  = (float*)(wp + WP_TOTAL);                  // <=3200 blocks * 64
    float* stats = part + (size_t)3200 * 64;                 // 7*64 fp32

    hipMemsetAsync(stats, 0, 7 * 64 * sizeof(float), stream);

    auto g1 = [](int n) { return dim3((unsigned)((n + 255) / 256)); };
    auto gm = [](int n) { return dim3((unsigned)((n + 127) / 128)); };   // 128 rows/block
    int nb0 = (N0 + 127) / 128;
    int nb1 = (N1 + 127) / 128;

    int prep_threads = N0 + 512 + 128 * (27 * 5 + 8);
    prep_kernel<<<g1(prep_threads), 256, 0, stream>>>(
        vf, Ws1, Ws2, Wd, Wr1a, Wr1b, Wr2a, Wr2b, xb, wp, N0);

    // stem1: xb -> yraw; act -> actA
    conv_stem1_mfma<<<gm(N0), 256, 0, stream>>>(xb, nbr0, wp + O_S1, yraw, part, N0);
    reduce_stats_kernel<<<64, 256, 0, stream>>>(part, stats + 0 * 64, nb0);
    bn_relu_kernel<false, false><<<g1(N0), 256, 0, stream>>>(yraw, stats + 0 * 64, gam + 0, bet + 0, nullptr, actA, N0);
    // stem2: actA -> yraw; act -> actB
    conv_mfma_kernel<27><<<gm(N0), 256, 0, stream>>>(actA, nbr0, wp + O_S2, yraw, part, N0);
    reduce_stats_kernel<<<64, 256, 0, stream>>>(part, stats + 1 * 64, nb0);
    bn_relu_kernel<false, false><<<g1(N0), 256, 0, stream>>>(yraw, stats + 1 * 64, gam + 32, bet + 32, nullptr, actB, N0);
    // down: actB (N0 rows) -> yraw (N1); x1 -> actA
    conv_mfma_kernel<8><<<gm(N1), 256, 0, stream>>>(actB, down1, wp + O_DN, yraw, part, N1);
    reduce_stats_kernel<<<64, 256, 0, stream>>>(part, stats + 2 * 64, nb1);
    bn_relu_kernel<false, false><<<g1(N1), 256, 0, stream>>>(yraw, stats + 2 * 64, gam + 64, bet + 64, nullptr, actA, N1);
    // r1a: actA -> yraw; h -> actB
    conv_mfma_kernel<27><<<gm(N1), 256, 0, stream>>>(actA, nbr1, wp + O_R1A, yraw, part, N1);
    reduce_stats_kernel<<<64, 256, 0, stream>>>(part, stats + 3 * 64, nb1);
    bn_relu_kernel<false, false><<<g1(N1), 256, 0, stream>>>(yraw, stats + 3 * 64, gam + 96, bet + 96, nullptr, actB, N1);
    // r1b: actB -> yraw; x1' = relu(bn(yraw) + actA) -> actB
    conv_mfma_kernel<27><<<gm(N1), 256, 0, stream>>>(actB, nbr1, wp + O_R1B, yraw, part, N1);
    reduce_stats_kernel<<<64, 256, 0, stream>>>(part, stats + 4 * 64, nb1);
    bn_relu_kernel<false, true><<<g1(N1), 256, 0, stream>>>(yraw, stats + 4 * 64, gam + 128, bet + 128, actA, actB, N1);
    // r2a: actB -> yraw; h2 -> actA
    conv_mfma_kernel<27><<<gm(N1), 256, 0, stream>>>(actB, nbr1, wp + O_R2A, yraw, part, N1);
    reduce_stats_kernel<<<64, 256, 0, stream>>>(part, stats + 5 * 64, nb1);
    bn_relu_kernel<false, false><<<g1(N1), 256, 0, stream>>>(yraw, stats + 5 * 64, gam + 160, bet + 160, nullptr, actA, N1);
    // r2b: actA -> yraw; out = relu(bn(yraw) + actB) -> d_out (fp32)
    conv_mfma_kernel<27><<<gm(N1), 256, 0, stream>>>(actA, nbr1, wp + O_R2B, yraw, part, N1);
    reduce_stats_kernel<<<64, 256, 0, stream>>>(part, stats + 6 * 64, nb1);
    bn_relu_kernel<true, true><<<g1(N1), 256, 0, stream>>>(yraw, stats + 6 * 64, gam + 192, bet + 192, actB, d_out, N1);
}